// Round 1
// baseline (267.431 us; speedup 1.0000x reference)
//
#include <hip/hip_runtime.h>

// Kernel 1: E[b] = expm(t[b] * A), A = 0.5*(B - B^T), B = M + M0, 8x8.
// One block (64 threads) per t value; thread `lane` owns element (i,j) with
// i = lane>>3, j = lane&7. Taylor series: term_{k} = term_{k-1} * (tA) / k.
// ||tA||_F <~ 0.1 so 12 terms is exact to fp32 roundoff.
__global__ void expm_kernel(const float* __restrict__ M, const float* __restrict__ M0,
                            const float* __restrict__ t, float* __restrict__ E) {
    const int b = blockIdx.x;
    const int lane = threadIdx.x;            // 0..63
    const int i = lane >> 3;
    const int j = lane & 7;

    __shared__ float sA[64];                 // tA
    __shared__ float sP[64];                 // current Taylor term

    const float bij = M[i * 8 + j] + M0[i * 8 + j];
    const float bji = M[j * 8 + i] + M0[j * 8 + i];
    const float ta = t[b] * 0.5f * (bij - bji);

    sA[lane] = ta;
    float e = (i == j ? 1.0f : 0.0f) + ta;   // I + tA
    float p = ta;
    __syncthreads();

    for (int k = 2; k <= 12; ++k) {
        sP[lane] = p;
        __syncthreads();
        float s = 0.0f;
        #pragma unroll
        for (int l = 0; l < 8; ++l) {
            s = fmaf(sP[i * 8 + l], sA[l * 8 + j], s);
        }
        p = s * (1.0f / (float)k);
        e += p;
        __syncthreads();                     // protect sP before next overwrite
    }

    E[b * 64 + lane] = e;
}

// Kernel 2: out[t, n, i] = sum_j E[t][i][j] * x[n][j].
// grid = (ceil(N / (256*G)), T), block = 256. Each block serves one t;
// E_t staged through LDS into 64 registers per thread, amortized over G
// n-values per thread. x rows read as 2x float4 (L2-resident), out written
// as 2x float4 per thread -> contiguous cache-line coverage, no RFO.
#define APPLY_G 8

__global__ __launch_bounds__(256) void apply_kernel(const float* __restrict__ Eall,
                                                    const float* __restrict__ x,
                                                    float* __restrict__ out,
                                                    int N) {
    const int t = blockIdx.y;

    __shared__ float sE[64];
    if (threadIdx.x < 64) sE[threadIdx.x] = Eall[t * 64 + threadIdx.x];
    __syncthreads();

    float e[64];
    #pragma unroll
    for (int c = 0; c < 64; ++c) e[c] = sE[c];

    const int n0 = blockIdx.x * (256 * APPLY_G) + threadIdx.x;
    const float4* __restrict__ x4 = (const float4*)x;
    float4* __restrict__ o4 = (float4*)(out + (size_t)t * (size_t)N * 8);

    #pragma unroll
    for (int g = 0; g < APPLY_G; ++g) {
        const int n = n0 + g * 256;
        if (n < N) {
            const float4 a = x4[2 * n];
            const float4 b = x4[2 * n + 1];
            const float xs[8] = {a.x, a.y, a.z, a.w, b.x, b.y, b.z, b.w};
            float y[8];
            #pragma unroll
            for (int ii = 0; ii < 8; ++ii) {
                float s = 0.0f;
                #pragma unroll
                for (int jj = 0; jj < 8; ++jj) {
                    s = fmaf(e[ii * 8 + jj], xs[jj], s);
                }
                y[ii] = s;
            }
            o4[2 * n]     = make_float4(y[0], y[1], y[2], y[3]);
            o4[2 * n + 1] = make_float4(y[4], y[5], y[6], y[7]);
        }
    }
}

extern "C" void kernel_launch(void* const* d_in, const int* in_sizes, int n_in,
                              void* d_out, int out_size, void* d_ws, size_t ws_size,
                              hipStream_t stream) {
    const float* x  = (const float*)d_in[0];   // [N, 8]
    const float* t  = (const float*)d_in[1];   // [T]
    const float* M  = (const float*)d_in[2];   // [8, 8]
    const float* M0 = (const float*)d_in[3];   // [8, 8]
    float* out = (float*)d_out;                // [T, N, 8]
    float* E = (float*)d_ws;                   // [T, 64] scratch (T*256 bytes)

    const int N = in_sizes[0] / 8;
    const int T = in_sizes[1];

    hipLaunchKernelGGL(expm_kernel, dim3(T), dim3(64), 0, stream, M, M0, t, E);

    const int gx = (N + 256 * APPLY_G - 1) / (256 * APPLY_G);
    hipLaunchKernelGGL(apply_kernel, dim3(gx, T), dim3(256), 0, stream, E, x, out, N);
}